// Round 9
// baseline (247.761 us; speedup 1.0000x reference)
//
#include <hip/hip_runtime.h>
#include <hip/hip_bf16.h>
#include <math.h>

// Problem constants (match reference)
#define N_NODES 50000
#define N_EDGES 800000
#define DIM 64
#define NEG_SLOPE 0.2f
#define EPS 1e-5f

typedef __attribute__((ext_vector_type(8))) short short8v;  // 8 bf16 (4 VGPRs)
typedef __attribute__((ext_vector_type(4))) float f32x4;    // MFMA accumulator

union frag_u { unsigned u[8]; short8v v[2]; };

__device__ __forceinline__ float lrelu(float v) { return fmaxf(v, NEG_SLOPE * v); }

__device__ __forceinline__ unsigned short bfbits(float v) {
    return __bfloat16_as_ushort(__float2bfloat16(v));
}
// packed pair f32->bf16
__device__ __forceinline__ unsigned pack2bf(float a, float b) {
    union { __hip_bfloat162 h; unsigned u; } cvt;
    cvt.h = __float22bfloat162_rn(make_float2(a, b));
    return cvt.u;
}

// Swizzled byte offset into a 128-byte-stride LDS tile (T2: byte ^= (row&7)<<4).
// (used by node_kernel only)
__device__ __forceinline__ unsigned swz(unsigned row, unsigned byteInRow) {
    return row * 128u + (byteInRow ^ ((row & 7u) << 4));
}

#define LDS_BUF 16384  // 128 rows x 128 bytes

// Fragment-layout weight store: matrix m, entry idx=(ks*4+g)*64+col holds
// short8 {bf16(W[k(ks,g,j)][col]), j=0..7}, used as MFMA A-operand (W^T).
// Matrices 0 (w1), 4 (pAw), 5 (pBw): standard k = 32ks+8g+j.
// Matrices 1 (w2), 2 (Bw), 3 (Cw): PERMUTED k = pi(ks,g,j) =
//   16*(2ks + (j>>2)) + 4g + (j&3)
// so that the previous phase's C-layout output (lane holds dims 16m+4hi+r of
// its edge) IS the next phase's B-fragment after cvt_pk packing — the k-space
// permutation is identical on the A side (baked here) and B side (free).
#define WFRAG_ENTRIES 512   // 2ks * 4g * 64col per matrix

#define SCANA_BLOCKS 49     // 49*1024 = 50176 >= 50000

// ---------------------------------------------------------------------------
// prep: blocks 0..5 convert weight matrices fp32 -> fragment bf16;
//       blocks 6..54 zero cnt (absorbs the memset dispatch)
// ---------------------------------------------------------------------------
__global__ __launch_bounds__(256) void prep_kernel(
    const float* __restrict__ w1, const float* __restrict__ w2,
    const float* __restrict__ Bw, const float* __restrict__ Cw,
    const float* __restrict__ pAw, const float* __restrict__ pBw,
    unsigned short* __restrict__ wbf, int* __restrict__ cnt)
{
    const int t = threadIdx.x;
    if (blockIdx.x >= 6) {
        const int idx = (blockIdx.x - 6) * 1024 + t * 4;
        if (idx + 3 < N_NODES) {
            int4 z = {0, 0, 0, 0};
            *(int4*)(cnt + idx) = z;
        } else {
#pragma unroll
            for (int i = 0; i < 4; ++i)
                if (idx + i < N_NODES) cnt[idx + i] = 0;
        }
        return;
    }
    const float* W;
    switch (blockIdx.x) {
        case 0: W = w1; break;
        case 1: W = w2; break;
        case 2: W = Bw; break;
        case 3: W = Cw; break;
        case 4: W = pAw; break;
        default: W = pBw; break;
    }
    const bool permuted = (blockIdx.x >= 1 && blockIdx.x <= 3);
#pragma unroll
    for (int ii = 0; ii < 2; ++ii) {
        const int idx = t * 2 + ii;          // 0..511
        const int ks  = idx >> 8;
        const int g   = (idx >> 6) & 3;
        const int col = idx & 63;
        unsigned short* o = wbf + (size_t)blockIdx.x * 4096 + (size_t)idx * 8;
#pragma unroll
        for (int j = 0; j < 8; ++j) {
            const int k = permuted ? (16 * (2 * ks + (j >> 2)) + 4 * g + (j & 3))
                                   : (32 * ks + 8 * g + j);
            o[j] = bfbits(W[k * DIM + col]);
        }
    }
}

// fragment fetch helper (m = matrix id, ks = k-step)
__device__ __forceinline__ short8v wfrag(const unsigned short* wbf, int m, int ks,
                                         int g, int col) {
    return ((const short8v*)wbf)[m * WFRAG_ENTRIES + (ks * 4 + g) * 64 + col];
}

// ---------------------------------------------------------------------------
// Node pooling via MFMA (unchanged; matrices 4,5 standard layout)
// ---------------------------------------------------------------------------
__global__ __launch_bounds__(256) void node_kernel(
    const float* __restrict__ V,
    const unsigned short* __restrict__ wbf,
    const float* __restrict__ pAb, const float* __restrict__ pBb,
    float* __restrict__ Vp)
{
    __shared__ __align__(16) unsigned char sm[2 * LDS_BUF];
    unsigned char* bufA = sm;
    unsigned char* bufB = sm + LDS_BUF;

    const int t    = threadIdx.x;
    const int w    = t >> 6;
    const int lane = t & 63;
    const int g    = lane >> 4;
    const int c    = lane & 15;
    const int col  = 16 * w + c;
    const unsigned colbyte = (unsigned)col * 2;
    const int base = blockIdx.x * 128;

    {
        const int row = t >> 1;
        const int n = base + row;
        if (n < N_NODES) {
            const float4* Vr = (const float4*)(V + (size_t)n * DIM + (t & 1) * 32);
#pragma unroll
            for (int ci = 0; ci < 4; ++ci) {
                float4 qa = Vr[2 * ci];
                float4 qb = Vr[2 * ci + 1];
                uint4 u;
                u.x = pack2bf(lrelu(qa.x), lrelu(qa.y));
                u.y = pack2bf(lrelu(qa.z), lrelu(qa.w));
                u.z = pack2bf(lrelu(qb.x), lrelu(qb.y));
                u.w = pack2bf(lrelu(qb.z), lrelu(qb.w));
                *(uint4*)(bufA + swz(row, (t & 1) * 64 + 16 * ci)) = u;
            }
        } else {
            uint4 z = {0u, 0u, 0u, 0u};
#pragma unroll
            for (int ci = 0; ci < 4; ++ci)
                *(uint4*)(bufA + swz(row, (t & 1) * 64 + 16 * ci)) = z;
        }
    }

    const short8v af0 = wfrag(wbf, 4, 0, g, col), af1 = wfrag(wbf, 4, 1, g, col);
    const short8v bf0 = wfrag(wbf, 5, 0, g, col), bf1 = wfrag(wbf, 5, 1, g, col);
    const float bbA = pAb[col], bbB = pBb[col];

    __syncthreads();

#pragma unroll
    for (int mt = 0; mt < 8; ++mt) {
        const int arow = mt * 16 + c;
        short8v a0 = *(const short8v*)(bufA + swz(arow, 16 * g));
        short8v a1 = *(const short8v*)(bufA + swz(arow, 64 + 16 * g));
        f32x4 acc = {0.f, 0.f, 0.f, 0.f};
        acc = __builtin_amdgcn_mfma_f32_16x16x32_bf16(a0, af0, acc, 0, 0, 0);
        acc = __builtin_amdgcn_mfma_f32_16x16x32_bf16(a1, af1, acc, 0, 0, 0);
#pragma unroll
        for (int r = 0; r < 4; ++r) {
            const float v = lrelu(acc[r] + bbA);
            *(unsigned short*)(bufB + swz(mt * 16 + 4 * g + r, colbyte)) = bfbits(v);
        }
    }
    __syncthreads();

#pragma unroll
    for (int mt = 0; mt < 8; ++mt) {
        const int arow = mt * 16 + c;
        short8v a0 = *(const short8v*)(bufB + swz(arow, 16 * g));
        short8v a1 = *(const short8v*)(bufB + swz(arow, 64 + 16 * g));
        f32x4 acc = {0.f, 0.f, 0.f, 0.f};
        acc = __builtin_amdgcn_mfma_f32_16x16x32_bf16(a0, bf0, acc, 0, 0, 0);
        acc = __builtin_amdgcn_mfma_f32_16x16x32_bf16(a1, bf1, acc, 0, 0, 0);
#pragma unroll
        for (int r = 0; r < 4; ++r) {
            const int n = base + mt * 16 + 4 * g + r;
            if (n < N_NODES) Vp[(size_t)n * DIM + col] = acc[r] + bbB;
        }
    }
}

// ---------------------------------------------------------------------------
// hist: per-dst count AND per-edge rank (slot within its node)
// ---------------------------------------------------------------------------
__global__ __launch_bounds__(256) void hist_kernel(
    const int* __restrict__ dst, int* __restrict__ cnt, int* __restrict__ rank)
{
    const int e = blockIdx.x * 256 + threadIdx.x;   // 800000 % 256 == 0
    rank[e] = atomicAdd(&cnt[dst[e]], 1);
}

// ---------------------------------------------------------------------------
// two-level scan
// ---------------------------------------------------------------------------
__global__ __launch_bounds__(256) void scanA_kernel(
    const int* __restrict__ cnt, int* __restrict__ lofs, int* __restrict__ btot)
{
    __shared__ int ts[256];
    const int t = threadIdx.x;
    const int nb = blockIdx.x * 1024 + t * 4;
    int4 c = {0, 0, 0, 0};
    if (nb + 3 < N_NODES) {
        c = *(const int4*)(cnt + nb);
    } else {
        if (nb + 0 < N_NODES) c.x = cnt[nb + 0];
        if (nb + 1 < N_NODES) c.y = cnt[nb + 1];
        if (nb + 2 < N_NODES) c.z = cnt[nb + 2];
        if (nb + 3 < N_NODES) c.w = cnt[nb + 3];
    }
    ts[t] = c.x + c.y + c.z + c.w;
    __syncthreads();
    for (int off = 1; off < 256; off <<= 1) {
        const int add = (t >= off) ? ts[t - off] : 0;
        __syncthreads();
        ts[t] += add;
        __syncthreads();
    }
    int4 o;
    o.x = (t == 0) ? 0 : ts[t - 1];
    o.y = o.x + c.x;
    o.z = o.y + c.y;
    o.w = o.z + c.z;
    if (nb + 3 < N_NODES) {
        *(int4*)(lofs + nb) = o;
    } else {
        if (nb + 0 < N_NODES) lofs[nb + 0] = o.x;
        if (nb + 1 < N_NODES) lofs[nb + 1] = o.y;
        if (nb + 2 < N_NODES) lofs[nb + 2] = o.z;
        if (nb + 3 < N_NODES) lofs[nb + 3] = o.w;
    }
    if (t == 255) btot[blockIdx.x] = ts[255];
}

__global__ __launch_bounds__(64) void scanB_kernel(
    const int* __restrict__ btot, int* __restrict__ bbase)
{
    const int t = threadIdx.x;    // one wave
    const int own = (t < SCANA_BLOCKS) ? btot[t] : 0;
    int v = own;
    for (int off = 1; off < 64; off <<= 1) {
        const int u = __shfl_up(v, off, 64);
        if (t >= off) v += u;
    }
    if (t < SCANA_BLOCKS) bbase[t] = v - own;   // exclusive
}

// ---------------------------------------------------------------------------
// ALL-REGISTER transposed-dual MFMA edge pipeline. ZERO LDS, ZERO barriers.
// 256 threads = 4 waves; each wave owns 16 edges (edge = lane&15 of its tile).
// Every GEMM: D^T = W^T (A, from wbf) x X^T (B, in registers).
// C-output (lane = dims 16m+4hi+r of edge c) becomes the next B-fragment by
// plain cvt_pk packing, because pi is baked into w2/Bw/Cw fragments (see prep).
// ---------------------------------------------------------------------------
__global__ __launch_bounds__(256) void edge_kernel(
    const float* __restrict__ E,
    const int* __restrict__ src, const int* __restrict__ dst,
    const int* __restrict__ rank,
    const int* __restrict__ lofs, const int* __restrict__ bbase,
    const unsigned short* __restrict__ wbf,
    const float* __restrict__ b1, const float* __restrict__ b2,
    const float* __restrict__ Bb, const float* __restrict__ Cb,
    const float* __restrict__ Vp,
    __hip_bfloat16* __restrict__ msg)
{
    const int t    = threadIdx.x;
    const int lane = t & 63;
    const int c    = lane & 15;
    const int hi   = lane >> 4;
    const int e    = blockIdx.x * 64 + (t >> 6) * 16 + c;  // this lane's edge

    // ---- early scattered loads: CSR slot, src, Vp gather (hide under GEMMs)
    const int d_my = dst[e];
    const int s0   = src[e];
    const int pos  = lofs[d_my] + bbase[d_my >> 10] + rank[e];

    float4 vpre[4];
#pragma unroll
    for (int m = 0; m < 4; ++m)
        vpre[m] = *(const float4*)(Vp + (size_t)s0 * DIM + 16 * m + 4 * hi);

    // ---- E row -> B-fragments (standard k order: k = 32ks + 8hi + j) ----
    short8v xb0, xb1;
    {
        const float* Ep = E + (size_t)e * DIM + 8 * hi;
        const float4 qa = *(const float4*)(Ep + 0);
        const float4 qb = *(const float4*)(Ep + 4);
        const float4 qc = *(const float4*)(Ep + 32);
        const float4 qd = *(const float4*)(Ep + 36);
        frag_u f;
        f.u[0] = pack2bf(qa.x, qa.y); f.u[1] = pack2bf(qa.z, qa.w);
        f.u[2] = pack2bf(qb.x, qb.y); f.u[3] = pack2bf(qb.z, qb.w);
        f.u[4] = pack2bf(qc.x, qc.y); f.u[5] = pack2bf(qc.z, qc.w);
        f.u[6] = pack2bf(qd.x, qd.y); f.u[7] = pack2bf(qd.z, qd.w);
        xb0 = f.v[0]; xb1 = f.v[1];
    }

    // One relu phase: xb <- relu(W^T x + b). Output C-layout packs directly
    // into the next B-fragments (pi baked into the NEXT phase's weights).
#define PHASE(MAT, BIASP)                                                         \
    {                                                                             \
        frag_u nx;                                                                \
        _Pragma("unroll")                                                         \
        for (int m = 0; m < 4; ++m) {                                             \
            const short8v a0 = wfrag(wbf, MAT, 0, hi, 16 * m + c);                \
            const short8v a1 = wfrag(wbf, MAT, 1, hi, 16 * m + c);                \
            f32x4 acc = {0.f, 0.f, 0.f, 0.f};                                     \
            acc = __builtin_amdgcn_mfma_f32_16x16x32_bf16(a0, xb0, acc, 0, 0, 0); \
            acc = __builtin_amdgcn_mfma_f32_16x16x32_bf16(a1, xb1, acc, 0, 0, 0); \
            const float4 bias = *(const float4*)(BIASP + 16 * m + 4 * hi);        \
            nx.u[2 * m]     = pack2bf(fmaxf(acc[0] + bias.x, 0.f),                \
                                      fmaxf(acc[1] + bias.y, 0.f));               \
            nx.u[2 * m + 1] = pack2bf(fmaxf(acc[2] + bias.z, 0.f),                \
                                      fmaxf(acc[3] + bias.w, 0.f));               \
        }                                                                         \
        xb0 = nx.v[0]; xb1 = nx.v[1];                                             \
    }

    PHASE(0, b1);   // x1 = relu(E @ w1 + b1)   (w1 standard, E standard)
    PHASE(1, b2);   // x2 = relu(x1 @ w2 + b2)  (w2 permuted)
#undef PHASE

    // ---- phase 3: gate/shift GEMMs (Bw/Cw permuted) + message + store ----
#pragma unroll
    for (int m = 0; m < 4; ++m) {
        const short8v a0B = wfrag(wbf, 2, 0, hi, 16 * m + c);
        const short8v a1B = wfrag(wbf, 2, 1, hi, 16 * m + c);
        const short8v a0C = wfrag(wbf, 3, 0, hi, 16 * m + c);
        const short8v a1C = wfrag(wbf, 3, 1, hi, 16 * m + c);
        f32x4 gb = {0.f, 0.f, 0.f, 0.f};
        gb = __builtin_amdgcn_mfma_f32_16x16x32_bf16(a0B, xb0, gb, 0, 0, 0);
        gb = __builtin_amdgcn_mfma_f32_16x16x32_bf16(a1B, xb1, gb, 0, 0, 0);
        f32x4 sc = {0.f, 0.f, 0.f, 0.f};
        sc = __builtin_amdgcn_mfma_f32_16x16x32_bf16(a0C, xb0, sc, 0, 0, 0);
        sc = __builtin_amdgcn_mfma_f32_16x16x32_bf16(a1C, xb1, sc, 0, 0, 0);
        const float4 biasB = *(const float4*)(Bb + 16 * m + 4 * hi);
        const float4 biasC = *(const float4*)(Cb + 16 * m + 4 * hi);
        const float* vp = (const float*)&vpre[m];
        const float* bBp = (const float*)&biasB;
        const float* bCp = (const float*)&biasC;
        float mm[4];
#pragma unroll
        for (int r = 0; r < 4; ++r) {
            const float gate = 1.f / (1.f + __expf(-(gb[r] + bBp[r])));
            float q = fmaf(gate, vp[r], sc[r] + bCp[r]);
            q = fmaxf(q, EPS);
            mm[r] = q * q;
        }
        uint2 p;
        p.x = pack2bf(mm[0], mm[1]);
        p.y = pack2bf(mm[2], mm[3]);
        *(uint2*)((unsigned short*)msg + (size_t)pos * DIM + 16 * m + 4 * hi) = p;
    }
}

// ---------------------------------------------------------------------------
// Aggregate: one wave per node; 8 edges per trip via uint4, shfl_xor reduce.
// ---------------------------------------------------------------------------
__global__ __launch_bounds__(256) void aggregate_kernel(
    const __hip_bfloat16* __restrict__ msg,
    const int* __restrict__ lofs, const int* __restrict__ bbase,
    const int* __restrict__ cnt,
    float* __restrict__ out)
{
    const int n = (blockIdx.x * 256 + threadIdx.x) >> 6;
    const int lane = threadIdx.x & 63;
    if (n >= N_NODES) return;
    const int start = lofs[n] + bbase[n >> 10];
    const int deg = cnt[n];
    const int rowg = lane >> 3;
    const int dblk = lane & 7;

    const unsigned short* bp = (const unsigned short*)msg + (size_t)start * DIM + dblk * 8;
    float acc0 = 0.f, acc1 = 0.f, acc2 = 0.f, acc3 = 0.f;
    float acc4 = 0.f, acc5 = 0.f, acc6 = 0.f, acc7 = 0.f;
    for (int i = 0; i < deg; i += 8) {
        const int r = i + rowg;
        if (r < deg) {
            const uint4 u = *(const uint4*)(bp + (size_t)r * DIM);
            acc0 += __uint_as_float(u.x << 16);
            acc1 += __uint_as_float(u.x & 0xffff0000u);
            acc2 += __uint_as_float(u.y << 16);
            acc3 += __uint_as_float(u.y & 0xffff0000u);
            acc4 += __uint_as_float(u.z << 16);
            acc5 += __uint_as_float(u.z & 0xffff0000u);
            acc6 += __uint_as_float(u.w << 16);
            acc7 += __uint_as_float(u.w & 0xffff0000u);
        }
    }
#pragma unroll
    for (int m = 8; m <= 32; m <<= 1) {
        acc0 += __shfl_xor(acc0, m, 64);
        acc1 += __shfl_xor(acc1, m, 64);
        acc2 += __shfl_xor(acc2, m, 64);
        acc3 += __shfl_xor(acc3, m, 64);
        acc4 += __shfl_xor(acc4, m, 64);
        acc5 += __shfl_xor(acc5, m, 64);
        acc6 += __shfl_xor(acc6, m, 64);
        acc7 += __shfl_xor(acc7, m, 64);
    }
    if (rowg == 0) {
        const float dinv = (deg > 0) ? 1.0f / (float)deg : 0.0f;
        float4 o0, o1;
        o0.x = sqrtf(acc0 * dinv); o0.y = sqrtf(acc1 * dinv);
        o0.z = sqrtf(acc2 * dinv); o0.w = sqrtf(acc3 * dinv);
        o1.x = sqrtf(acc4 * dinv); o1.y = sqrtf(acc5 * dinv);
        o1.z = sqrtf(acc6 * dinv); o1.w = sqrtf(acc7 * dinv);
        float4* op = (float4*)(out + (size_t)n * DIM + dblk * 8);
        op[0] = o0;
        op[1] = o1;
    }
}

extern "C" void kernel_launch(void* const* d_in, const int* in_sizes, int n_in,
                              void* d_out, int out_size, void* d_ws, size_t ws_size,
                              hipStream_t stream) {
    const float* V   = (const float*)d_in[0];
    const float* E   = (const float*)d_in[1];
    const int*   src = (const int*)d_in[2];
    const int*   dst = (const int*)d_in[3];
    const float* w1  = (const float*)d_in[4];
    const float* b1  = (const float*)d_in[5];
    const float* w2  = (const float*)d_in[6];
    const float* b2  = (const float*)d_in[7];
    const float* Bw  = (const float*)d_in[8];
    const float* Bb  = (const float*)d_in[9];
    const float* Cw  = (const float*)d_in[10];
    const float* Cb  = (const float*)d_in[11];
    const float* pAw = (const float*)d_in[12];
    const float* pAb = (const float*)d_in[13];
    const float* pBw = (const float*)d_in[14];
    const float* pBb = (const float*)d_in[15];

    float* out = (float*)d_out;

    // workspace layout
    char* p = (char*)d_ws;
    float* Vp = (float*)p;                    p += (size_t)N_NODES * DIM * sizeof(float);
    __hip_bfloat16* msg = (__hip_bfloat16*)p; p += (size_t)N_EDGES * DIM * 2;
    int* cnt  = (int*)p; p += (size_t)50176 * 4;
    int* lofs = (int*)p; p += (size_t)50176 * 4;
    int* rank = (int*)p; p += (size_t)N_EDGES * 4;
    unsigned short* wbf = (unsigned short*)p; p += (size_t)6 * 4096 * 2;
    int* btot  = (int*)p; p += (size_t)64 * 4;
    int* bbase = (int*)p; p += (size_t)64 * 4;

    prep_kernel<<<6 + SCANA_BLOCKS, 256, 0, stream>>>(w1, w2, Bw, Cw, pAw, pBw, wbf, cnt);
    hist_kernel<<<N_EDGES / 256, 256, 0, stream>>>(dst, cnt, rank);
    node_kernel<<<(N_NODES + 127) / 128, 256, 0, stream>>>(V, wbf, pAb, pBb, Vp);
    scanA_kernel<<<SCANA_BLOCKS, 256, 0, stream>>>(cnt, lofs, btot);
    scanB_kernel<<<1, 64, 0, stream>>>(btot, bbase);
    edge_kernel<<<N_EDGES / 64, 256, 0, stream>>>(E, src, dst, rank, lofs, bbase, wbf,
                                                  b1, b2, Bb, Cb, Vp, msg);
    aggregate_kernel<<<(N_NODES * 64 + 255) / 256, 256, 0, stream>>>(msg, lofs, bbase, cnt, out);
}

// Round 10
// 195.660 us; speedup vs baseline: 1.2663x; 1.2663x over previous
//
#include <hip/hip_runtime.h>
#include <hip/hip_bf16.h>
#include <math.h>

// Problem constants (match reference)
#define N_NODES 50000
#define N_EDGES 800000
#define DIM 64
#define NEG_SLOPE 0.2f
#define EPS 1e-5f

typedef __attribute__((ext_vector_type(8))) short short8v;  // 8 bf16 (4 VGPRs)
typedef __attribute__((ext_vector_type(4))) float f32x4;    // MFMA accumulator

__device__ __forceinline__ float lrelu(float v) { return fmaxf(v, NEG_SLOPE * v); }

__device__ __forceinline__ unsigned short bfbits(float v) {
    return __bfloat16_as_ushort(__float2bfloat16(v));
}
// packed pair f32->bf16
__device__ __forceinline__ unsigned pack2bf(float a, float b) {
    union { __hip_bfloat162 h; unsigned u; } cvt;
    cvt.h = __float22bfloat162_rn(make_float2(a, b));
    return cvt.u;
}

// Swizzled byte offset into a 128-byte-stride LDS tile (T2: byte ^= (row&7)<<4).
__device__ __forceinline__ unsigned swz(unsigned row, unsigned byteInRow) {
    return row * 128u + (byteInRow ^ ((row & 7u) << 4));
}

#define LDS_BUF 16384  // 128 rows x 128 bytes

// Fragment-layout weight store: matrix m, entry idx=(ks*4+g)*64+col holds
// short8 {bf16(W[(32ks+8g+j)*64+col]), j=0..7}. One b128 load per fragment.
#define WFRAG_ENTRIES 512   // 2ks * 4g * 64col per matrix

#define SCANA_BLOCKS 49     // 49*1024 = 50176 >= 50000

// ---------------------------------------------------------------------------
// prep: blocks 0..5 convert weight matrices fp32 -> fragment bf16;
//       blocks 6..54 zero cnt (absorbs the memset dispatch)
// ---------------------------------------------------------------------------
__global__ __launch_bounds__(256) void prep_kernel(
    const float* __restrict__ w1, const float* __restrict__ w2,
    const float* __restrict__ Bw, const float* __restrict__ Cw,
    const float* __restrict__ pAw, const float* __restrict__ pBw,
    unsigned short* __restrict__ wbf, int* __restrict__ cnt)
{
    const int t = threadIdx.x;
    if (blockIdx.x >= 6) {
        const int idx = (blockIdx.x - 6) * 1024 + t * 4;
        if (idx + 3 < N_NODES) {
            int4 z = {0, 0, 0, 0};
            *(int4*)(cnt + idx) = z;
        } else {
#pragma unroll
            for (int i = 0; i < 4; ++i)
                if (idx + i < N_NODES) cnt[idx + i] = 0;
        }
        return;
    }
    const float* W;
    switch (blockIdx.x) {
        case 0: W = w1; break;
        case 1: W = w2; break;
        case 2: W = Bw; break;
        case 3: W = Cw; break;
        case 4: W = pAw; break;
        default: W = pBw; break;
    }
#pragma unroll
    for (int ii = 0; ii < 2; ++ii) {
        const int idx = t * 2 + ii;          // 0..511
        const int ks  = idx >> 8;
        const int g   = (idx >> 6) & 3;
        const int col = idx & 63;
        unsigned short* o = wbf + (size_t)blockIdx.x * 4096 + (size_t)idx * 8;
#pragma unroll
        for (int j = 0; j < 8; ++j)
            o[j] = bfbits(W[(32 * ks + 8 * g + j) * DIM + col]);
    }
}

// fragment fetch helper (m = matrix id, ks = k-step)
__device__ __forceinline__ short8v wfrag(const unsigned short* wbf, int m, int ks,
                                         int g, int col) {
    return ((const short8v*)wbf)[m * WFRAG_ENTRIES + (ks * 4 + g) * 64 + col];
}

// ---------------------------------------------------------------------------
// Node pooling via MFMA: Vp = lrelu(lrelu(V)@pAw+pAb)@pBw+pBb
// ---------------------------------------------------------------------------
__global__ __launch_bounds__(256) void node_kernel(
    const float* __restrict__ V,
    const unsigned short* __restrict__ wbf,
    const float* __restrict__ pAb, const float* __restrict__ pBb,
    float* __restrict__ Vp)
{
    __shared__ __align__(16) unsigned char sm[2 * LDS_BUF];
    unsigned char* bufA = sm;
    unsigned char* bufB = sm + LDS_BUF;

    const int t    = threadIdx.x;
    const int w    = t >> 6;
    const int lane = t & 63;
    const int g    = lane >> 4;
    const int c    = lane & 15;
    const int col  = 16 * w + c;
    const unsigned colbyte = (unsigned)col * 2;
    const int base = blockIdx.x * 128;

    {
        const int row = t >> 1;
        const int n = base + row;
        if (n < N_NODES) {
            const float4* Vr = (const float4*)(V + (size_t)n * DIM + (t & 1) * 32);
#pragma unroll
            for (int ci = 0; ci < 4; ++ci) {
                float4 qa = Vr[2 * ci];
                float4 qb = Vr[2 * ci + 1];
                uint4 u;
                u.x = pack2bf(lrelu(qa.x), lrelu(qa.y));
                u.y = pack2bf(lrelu(qa.z), lrelu(qa.w));
                u.z = pack2bf(lrelu(qb.x), lrelu(qb.y));
                u.w = pack2bf(lrelu(qb.z), lrelu(qb.w));
                *(uint4*)(bufA + swz(row, (t & 1) * 64 + 16 * ci)) = u;
            }
        } else {
            uint4 z = {0u, 0u, 0u, 0u};
#pragma unroll
            for (int ci = 0; ci < 4; ++ci)
                *(uint4*)(bufA + swz(row, (t & 1) * 64 + 16 * ci)) = z;
        }
    }

    const short8v af0 = wfrag(wbf, 4, 0, g, col), af1 = wfrag(wbf, 4, 1, g, col);
    const short8v bf0 = wfrag(wbf, 5, 0, g, col), bf1 = wfrag(wbf, 5, 1, g, col);
    const float bbA = pAb[col], bbB = pBb[col];

    __syncthreads();

#pragma unroll
    for (int mt = 0; mt < 8; ++mt) {
        const int arow = mt * 16 + c;
        short8v a0 = *(const short8v*)(bufA + swz(arow, 16 * g));
        short8v a1 = *(const short8v*)(bufA + swz(arow, 64 + 16 * g));
        f32x4 acc = {0.f, 0.f, 0.f, 0.f};
        acc = __builtin_amdgcn_mfma_f32_16x16x32_bf16(a0, af0, acc, 0, 0, 0);
        acc = __builtin_amdgcn_mfma_f32_16x16x32_bf16(a1, af1, acc, 0, 0, 0);
#pragma unroll
        for (int r = 0; r < 4; ++r) {
            const float v = lrelu(acc[r] + bbA);
            *(unsigned short*)(bufB + swz(mt * 16 + 4 * g + r, colbyte)) = bfbits(v);
        }
    }
    __syncthreads();

#pragma unroll
    for (int mt = 0; mt < 8; ++mt) {
        const int arow = mt * 16 + c;
        short8v a0 = *(const short8v*)(bufB + swz(arow, 16 * g));
        short8v a1 = *(const short8v*)(bufB + swz(arow, 64 + 16 * g));
        f32x4 acc = {0.f, 0.f, 0.f, 0.f};
        acc = __builtin_amdgcn_mfma_f32_16x16x32_bf16(a0, bf0, acc, 0, 0, 0);
        acc = __builtin_amdgcn_mfma_f32_16x16x32_bf16(a1, bf1, acc, 0, 0, 0);
#pragma unroll
        for (int r = 0; r < 4; ++r) {
            const int n = base + mt * 16 + 4 * g + r;
            if (n < N_NODES) Vp[(size_t)n * DIM + col] = acc[r] + bbB;
        }
    }
}

// ---------------------------------------------------------------------------
// hist: per-dst count AND per-edge rank (slot within its node)
// ---------------------------------------------------------------------------
__global__ __launch_bounds__(256) void hist_kernel(
    const int* __restrict__ dst, int* __restrict__ cnt, int* __restrict__ rank)
{
    const int e = blockIdx.x * 256 + threadIdx.x;   // 800000 % 256 == 0
    rank[e] = atomicAdd(&cnt[dst[e]], 1);
}

// ---------------------------------------------------------------------------
// two-level scan
// ---------------------------------------------------------------------------
__global__ __launch_bounds__(256) void scanA_kernel(
    const int* __restrict__ cnt, int* __restrict__ lofs, int* __restrict__ btot)
{
    __shared__ int ts[256];
    const int t = threadIdx.x;
    const int nb = blockIdx.x * 1024 + t * 4;
    int4 c = {0, 0, 0, 0};
    if (nb + 3 < N_NODES) {
        c = *(const int4*)(cnt + nb);
    } else {
        if (nb + 0 < N_NODES) c.x = cnt[nb + 0];
        if (nb + 1 < N_NODES) c.y = cnt[nb + 1];
        if (nb + 2 < N_NODES) c.z = cnt[nb + 2];
        if (nb + 3 < N_NODES) c.w = cnt[nb + 3];
    }
    ts[t] = c.x + c.y + c.z + c.w;
    __syncthreads();
    for (int off = 1; off < 256; off <<= 1) {
        const int add = (t >= off) ? ts[t - off] : 0;
        __syncthreads();
        ts[t] += add;
        __syncthreads();
    }
    int4 o;
    o.x = (t == 0) ? 0 : ts[t - 1];
    o.y = o.x + c.x;
    o.z = o.y + c.y;
    o.w = o.z + c.z;
    if (nb + 3 < N_NODES) {
        *(int4*)(lofs + nb) = o;
    } else {
        if (nb + 0 < N_NODES) lofs[nb + 0] = o.x;
        if (nb + 1 < N_NODES) lofs[nb + 1] = o.y;
        if (nb + 2 < N_NODES) lofs[nb + 2] = o.z;
        if (nb + 3 < N_NODES) lofs[nb + 3] = o.w;
    }
    if (t == 255) btot[blockIdx.x] = ts[255];
}

__global__ __launch_bounds__(64) void scanB_kernel(
    const int* __restrict__ btot, int* __restrict__ bbase)
{
    const int t = threadIdx.x;    // one wave
    const int own = (t < SCANA_BLOCKS) ? btot[t] : 0;
    int v = own;
    for (int off = 1; off < 64; off <<= 1) {
        const int u = __shfl_up(v, off, 64);
        if (t >= off) v += u;
    }
    if (t < SCANA_BLOCKS) bbase[t] = v - own;   // exclusive
}

// ---------------------------------------------------------------------------
// MFMA edge pipeline (r6 structure — best measured at 122 us).
// Block = 128 edges, 256 threads = 4 waves; fragment-layout weights (b128),
// Vp gather prefetched to registers; CSR slot staged in LDS by 128 threads.
// ---------------------------------------------------------------------------
__global__ __launch_bounds__(256) void edge_kernel(
    const float* __restrict__ E,
    const int* __restrict__ src, const int* __restrict__ dst,
    const int* __restrict__ rank,
    const int* __restrict__ lofs, const int* __restrict__ bbase,
    const unsigned short* __restrict__ wbf,
    const float* __restrict__ b1, const float* __restrict__ b2,
    const float* __restrict__ Bb, const float* __restrict__ Cb,
    const float* __restrict__ Vp,
    __hip_bfloat16* __restrict__ msg)
{
    __shared__ __align__(16) unsigned char sm[2 * LDS_BUF + 128 * 4];
    unsigned char* bufA = sm;
    unsigned char* bufB = sm + LDS_BUF;
    int* eposv = (int*)(sm + 2 * LDS_BUF);

    const int t    = threadIdx.x;
    const int w    = t >> 6;
    const int lane = t & 63;
    const int g    = lane >> 4;
    const int c    = lane & 15;
    const int col  = 16 * w + c;
    const unsigned colbyte = (unsigned)col * 2;
    const int base = blockIdx.x * 128;

    // ---- CSR slot via LDS (128 staging threads own the scattered chain) ----
    if (t < 128) {
        const int d = dst[base + t];
        eposv[t] = lofs[d] + bbase[d >> 10] + rank[base + t];
    }

    // ---- Vp gather prefetch: 32 independent chains, in flight during GEMMs
    float vpre[32];
#pragma unroll
    for (int mt = 0; mt < 8; ++mt) {
#pragma unroll
        for (int r = 0; r < 4; ++r) {
            const int sv = src[base + mt * 16 + 4 * g + r];
            vpre[mt * 4 + r] = Vp[(size_t)sv * DIM + col];
        }
    }

    // ---- stage E tile (fp32 -> bf16, swizzled) ----
    {
        const int row = t >> 1;
        const float4* Ep = (const float4*)(E + (size_t)(base + row) * DIM + (t & 1) * 32);
#pragma unroll
        for (int ci = 0; ci < 4; ++ci) {
            float4 qa = Ep[2 * ci];
            float4 qb = Ep[2 * ci + 1];
            uint4 u;
            u.x = pack2bf(qa.x, qa.y); u.y = pack2bf(qa.z, qa.w);
            u.z = pack2bf(qb.x, qb.y); u.w = pack2bf(qb.z, qb.w);
            *(uint4*)(bufA + swz(row, (t & 1) * 64 + 16 * ci)) = u;
        }
    }

    // ---- weight fragments: one b128 load each ----
    const short8v w1f0 = wfrag(wbf, 0, 0, g, col), w1f1 = wfrag(wbf, 0, 1, g, col);
    const short8v w2f0 = wfrag(wbf, 1, 0, g, col), w2f1 = wfrag(wbf, 1, 1, g, col);
    const short8v bwf0 = wfrag(wbf, 2, 0, g, col), bwf1 = wfrag(wbf, 2, 1, g, col);
    const short8v cwf0 = wfrag(wbf, 3, 0, g, col), cwf1 = wfrag(wbf, 3, 1, g, col);
    const float bb1 = b1[col], bb2 = b2[col], bbB = Bb[col], bbC = Cb[col];

    __syncthreads();

    // ---- layer 1: x1 = relu(E @ w1 + b1) : bufA -> bufB ----
#pragma unroll
    for (int mt = 0; mt < 8; ++mt) {
        const int arow = mt * 16 + c;
        short8v a0 = *(const short8v*)(bufA + swz(arow, 16 * g));
        short8v a1 = *(const short8v*)(bufA + swz(arow, 64 + 16 * g));
        f32x4 acc = {0.f, 0.f, 0.f, 0.f};
        acc = __builtin_amdgcn_mfma_f32_16x16x32_bf16(a0, w1f0, acc, 0, 0, 0);
        acc = __builtin_amdgcn_mfma_f32_16x16x32_bf16(a1, w1f1, acc, 0, 0, 0);
#pragma unroll
        for (int r = 0; r < 4; ++r) {
            const float v = fmaxf(acc[r] + bb1, 0.f);
            *(unsigned short*)(bufB + swz(mt * 16 + 4 * g + r, colbyte)) = bfbits(v);
        }
    }
    __syncthreads();

    // ---- layer 2: x2 = relu(x1 @ w2 + b2) : bufB -> bufA ----
#pragma unroll
    for (int mt = 0; mt < 8; ++mt) {
        const int arow = mt * 16 + c;
        short8v a0 = *(const short8v*)(bufB + swz(arow, 16 * g));
        short8v a1 = *(const short8v*)(bufB + swz(arow, 64 + 16 * g));
        f32x4 acc = {0.f, 0.f, 0.f, 0.f};
        acc = __builtin_amdgcn_mfma_f32_16x16x32_bf16(a0, w2f0, acc, 0, 0, 0);
        acc = __builtin_amdgcn_mfma_f32_16x16x32_bf16(a1, w2f1, acc, 0, 0, 0);
#pragma unroll
        for (int r = 0; r < 4; ++r) {
            const float v = fmaxf(acc[r] + bb2, 0.f);
            *(unsigned short*)(bufA + swz(mt * 16 + 4 * g + r, colbyte)) = bfbits(v);
        }
    }
    __syncthreads();

    // ---- gate + shift GEMMs fused with message: bufA(x2) -> bufB(msg) ----
#pragma unroll
    for (int mt = 0; mt < 8; ++mt) {
        const int arow = mt * 16 + c;
        short8v a0 = *(const short8v*)(bufA + swz(arow, 16 * g));
        short8v a1 = *(const short8v*)(bufA + swz(arow, 64 + 16 * g));
        f32x4 t0 = {0.f, 0.f, 0.f, 0.f};
        t0 = __builtin_amdgcn_mfma_f32_16x16x32_bf16(a0, bwf0, t0, 0, 0, 0);
        t0 = __builtin_amdgcn_mfma_f32_16x16x32_bf16(a1, bwf1, t0, 0, 0, 0);
        f32x4 t1 = {0.f, 0.f, 0.f, 0.f};
        t1 = __builtin_amdgcn_mfma_f32_16x16x32_bf16(a0, cwf0, t1, 0, 0, 0);
        t1 = __builtin_amdgcn_mfma_f32_16x16x32_bf16(a1, cwf1, t1, 0, 0, 0);
#pragma unroll
        for (int r = 0; r < 4; ++r) {
            const float gate = 1.f / (1.f + __expf(-(t0[r] + bbB)));
            const float sh = t1[r] + bbC;
            float m = fmaf(gate, vpre[mt * 4 + r], sh);
            m = fmaxf(m, EPS);
            m = m * m;
            *(unsigned short*)(bufB + swz(mt * 16 + 4 * g + r, colbyte)) = bfbits(m);
        }
    }
    __syncthreads();

    // ---- copy-out to CSR slot: 2 threads per edge row, 64B each ----
    {
        const int row = t >> 1;
        const int pos = eposv[row];
        uint4 v[4];
#pragma unroll
        for (int ci = 0; ci < 4; ++ci)
            v[ci] = *(const uint4*)(bufB + swz(row, (t & 1) * 64 + 16 * ci));
        uint4* dp = (uint4*)((unsigned short*)msg + (size_t)pos * DIM + (t & 1) * 32);
#pragma unroll
        for (int ci = 0; ci < 4; ++ci) dp[ci] = v[ci];
    }
}

// ---------------------------------------------------------------------------
// Aggregate: one wave per node; 8 edges per trip via uint4, shfl_xor reduce.
// ---------------------------------------------------------------------------
__global__ __launch_bounds__(256) void aggregate_kernel(
    const __hip_bfloat16* __restrict__ msg,
    const int* __restrict__ lofs, const int* __restrict__ bbase,
    const int* __restrict__ cnt,
    float* __restrict__ out)
{
    const int n = (blockIdx.x * 256 + threadIdx.x) >> 6;
    const int lane = threadIdx.x & 63;
    if (n >= N_NODES) return;
    const int start = lofs[n] + bbase[n >> 10];
    const int deg = cnt[n];
    const int rowg = lane >> 3;
    const int dblk = lane & 7;

    const unsigned short* bp = (const unsigned short*)msg + (size_t)start * DIM + dblk * 8;
    float acc0 = 0.f, acc1 = 0.f, acc2 = 0.f, acc3 = 0.f;
    float acc4 = 0.f, acc5 = 0.f, acc6 = 0.f, acc7 = 0.f;
    for (int i = 0; i < deg; i += 8) {
        const int r = i + rowg;
        if (r < deg) {
            const uint4 u = *(const uint4*)(bp + (size_t)r * DIM);
            acc0 += __uint_as_float(u.x << 16);
            acc1 += __uint_as_float(u.x & 0xffff0000u);
            acc2 += __uint_as_float(u.y << 16);
            acc3 += __uint_as_float(u.y & 0xffff0000u);
            acc4 += __uint_as_float(u.z << 16);
            acc5 += __uint_as_float(u.z & 0xffff0000u);
            acc6 += __uint_as_float(u.w << 16);
            acc7 += __uint_as_float(u.w & 0xffff0000u);
        }
    }
#pragma unroll
    for (int m = 8; m <= 32; m <<= 1) {
        acc0 += __shfl_xor(acc0, m, 64);
        acc1 += __shfl_xor(acc1, m, 64);
        acc2 += __shfl_xor(acc2, m, 64);
        acc3 += __shfl_xor(acc3, m, 64);
        acc4 += __shfl_xor(acc4, m, 64);
        acc5 += __shfl_xor(acc5, m, 64);
        acc6 += __shfl_xor(acc6, m, 64);
        acc7 += __shfl_xor(acc7, m, 64);
    }
    if (rowg == 0) {
        const float dinv = (deg > 0) ? 1.0f / (float)deg : 0.0f;
        float4 o0, o1;
        o0.x = sqrtf(acc0 * dinv); o0.y = sqrtf(acc1 * dinv);
        o0.z = sqrtf(acc2 * dinv); o0.w = sqrtf(acc3 * dinv);
        o1.x = sqrtf(acc4 * dinv); o1.y = sqrtf(acc5 * dinv);
        o1.z = sqrtf(acc6 * dinv); o1.w = sqrtf(acc7 * dinv);
        float4* op = (float4*)(out + (size_t)n * DIM + dblk * 8);
        op[0] = o0;
        op[1] = o1;
    }
}

extern "C" void kernel_launch(void* const* d_in, const int* in_sizes, int n_in,
                              void* d_out, int out_size, void* d_ws, size_t ws_size,
                              hipStream_t stream) {
    const float* V   = (const float*)d_in[0];
    const float* E   = (const float*)d_in[1];
    const int*   src = (const int*)d_in[2];
    const int*   dst = (const int*)d_in[3];
    const float* w1  = (const float*)d_in[4];
    const float* b1  = (const float*)d_in[5];
    const float* w2  = (const float*)d_in[6];
    const float* b2  = (const float*)d_in[7];
    const float* Bw  = (const float*)d_in[8];
    const float* Bb  = (const float*)d_in[9];
    const float* Cw  = (const float*)d_in[10];
    const float* Cb  = (const float*)d_in[11];
    const float* pAw = (const float*)d_in[12];
    const float* pAb = (const float*)d_in[13];
    const float* pBw = (const float*)d_in[14];
    const float* pBb = (const float*)d_in[15];

    float* out = (float*)d_out;

    // workspace layout
    char* p = (char*)d_ws;
    float* Vp = (float*)p;                    p += (size_t)N_NODES * DIM * sizeof(float);
    __hip_bfloat16* msg = (__hip_bfloat16*)p; p += (size_t)N_EDGES * DIM * 2;
    int* cnt  = (int*)p; p += (size_t)50176 * 4;
    int* lofs = (int*)p; p += (size_t)50176 * 4;
    int* rank = (int*)p; p += (size_t)N_EDGES * 4;
    unsigned short* wbf = (unsigned short*)p; p += (size_t)6 * 4096 * 2;
    int* btot  = (int*)p; p += (size_t)64 * 4;
    int* bbase = (int*)p; p += (size_t)64 * 4;

    prep_kernel<<<6 + SCANA_BLOCKS, 256, 0, stream>>>(w1, w2, Bw, Cw, pAw, pBw, wbf, cnt);
    hist_kernel<<<N_EDGES / 256, 256, 0, stream>>>(dst, cnt, rank);
    node_kernel<<<(N_NODES + 127) / 128, 256, 0, stream>>>(V, wbf, pAb, pBb, Vp);
    scanA_kernel<<<SCANA_BLOCKS, 256, 0, stream>>>(cnt, lofs, btot);
    scanB_kernel<<<1, 64, 0, stream>>>(btot, bbase);
    edge_kernel<<<N_EDGES / 128, 256, 0, stream>>>(E, src, dst, rank, lofs, bbase, wbf,
                                                   b1, b2, Bb, Cb, Vp, msg);
    aggregate_kernel<<<(N_NODES * 64 + 255) / 256, 256, 0, stream>>>(msg, lofs, bbase, cnt, out);
}